// Round 1
// baseline (878.207 us; speedup 1.0000x reference)
//
#include <hip/hip_runtime.h>

#define N_NODES 50000
#define INC 300
#define KP1 320      // padded K for layer-1 GEMM
#define HID 512
#define OUTC 512

typedef unsigned short u16;
typedef __bf16 bf16;
typedef bf16 bf16x8 __attribute__((ext_vector_type(8)));
typedef float f32x4 __attribute__((ext_vector_type(4)));

__device__ inline u16 f32_to_bf16(float f) {
  unsigned u = __float_as_uint(f);
  u += 0x7FFFu + ((u >> 16) & 1u);   // round-to-nearest-even
  return (u16)(u >> 16);
}

__device__ inline void gload_lds16(const void* g, void* l) {
  __builtin_amdgcn_global_load_lds(
      (const __attribute__((address_space(1))) void*)g,
      (__attribute__((address_space(3))) void*)l, 16, 0, 0);
}

// ---------------- CSR build ----------------
__global__ void k_hist(const int* __restrict__ erow, int E, int* __restrict__ deg) {
  int i = blockIdx.x * blockDim.x + threadIdx.x;
  if (i < E) atomicAdd(&deg[erow[i]], 1);
}

__global__ __launch_bounds__(1024) void k_scan(const int* __restrict__ deg,
                                               int* __restrict__ rowstart) {
  __shared__ int part[1024];
  int tid = threadIdx.x;
  const int ch = (N_NODES + 1023) / 1024;
  int lo = tid * ch;
  int hi = lo + ch;
  if (lo > N_NODES) lo = N_NODES;
  if (hi > N_NODES) hi = N_NODES;
  int s = 0;
  for (int i = lo; i < hi; ++i) s += deg[i];
  part[tid] = s;
  __syncthreads();
  for (int off = 1; off < 1024; off <<= 1) {
    int v = (tid >= off) ? part[tid - off] : 0;
    __syncthreads();
    part[tid] += v;
    __syncthreads();
  }
  int run = (tid > 0) ? part[tid - 1] : 0;
  for (int i = lo; i < hi; ++i) { rowstart[i] = run; run += deg[i]; }
  if (tid == 1023) rowstart[N_NODES] = part[1023];
}

__global__ void k_scatter(const int* __restrict__ erow, int E,
                          const int* __restrict__ rowstart,
                          int* __restrict__ cursor, int* __restrict__ perm) {
  int i = blockIdx.x * blockDim.x + threadIdx.x;
  if (i < E) {
    int r = erow[i];
    int p = atomicAdd(&cursor[r], 1);
    perm[rowstart[r] + p] = i;
  }
}

// ---------------- weight f32 -> bf16 (zero-padded K) ----------------
__global__ void k_convw(const float* __restrict__ W, u16* __restrict__ Wb,
                        int K, int KPADc, int total) {
  int i = blockIdx.x * blockDim.x + threadIdx.x;
  if (i < total) {
    int r = i / KPADc, k = i - r * KPADc;
    Wb[i] = (k < K) ? f32_to_bf16(W[(size_t)r * K + k]) : (u16)0;
  }
}

// ---------------- SpMM layer 1: ax = A @ x   (f32 in, bf16 out, 300->pad320) ----
__global__ __launch_bounds__(256) void spmm_x(
    const float* __restrict__ x, const int* __restrict__ ecol,
    const float* __restrict__ ev, const int* __restrict__ perm,
    const int* __restrict__ rs, u16* __restrict__ ax) {
  int r = blockIdx.x;
  int tid = threadIdx.x;
  int s = rs[r], e = rs[r + 1];
  float a0 = 0.f, a1 = 0.f;
  int c1 = tid + 256;
  for (int i = s; i < e; ++i) {
    int ed = perm[i];
    int c = ecol[ed];
    float v = ev[ed];
    const float* xr = x + (size_t)c * INC;
    a0 += v * xr[tid];
    if (c1 < INC) a1 += v * xr[c1];
  }
  size_t o = (size_t)r * KP1;
  ax[o + tid] = f32_to_bf16(a0);
  if (c1 < KP1) ax[o + c1] = (c1 < INC) ? f32_to_bf16(a1) : (u16)0;
}

// ---------------- SpMM layer 2: ah = A @ h   (bf16 in, bf16 out, 512 wide) -----
__global__ __launch_bounds__(256) void spmm_h(
    const u16* __restrict__ h, const int* __restrict__ ecol,
    const float* __restrict__ ev, const int* __restrict__ perm,
    const int* __restrict__ rs, u16* __restrict__ ah) {
  int r = blockIdx.x;
  int tid = threadIdx.x;
  int s = rs[r], e = rs[r + 1];
  float a0 = 0.f, a1 = 0.f;
  for (int i = s; i < e; ++i) {
    int ed = perm[i];
    int c = ecol[ed];
    float v = ev[ed];
    unsigned u = *(const unsigned*)(h + (size_t)c * HID + tid * 2);
    a0 += v * __uint_as_float(u << 16);
    a1 += v * __uint_as_float(u & 0xFFFF0000u);
  }
  unsigned o0 = f32_to_bf16(a0);
  unsigned o1 = f32_to_bf16(a1);
  *(unsigned*)(ah + (size_t)r * HID + tid * 2) = o0 | (o1 << 16);
}

// ---------------- bf16 MFMA GEMM:  C[M,512] = A[M,KPAD] @ B[512,KPAD]^T + bias -
template <int KPAD, bool RELU, bool OUT_BF16>
__global__ __launch_bounds__(256) void gemm_nt(
    const u16* __restrict__ A, const u16* __restrict__ B,
    const float* __restrict__ bias, void* __restrict__ Cout, int M) {
  __shared__ __align__(16) u16 As[128 * 32];
  __shared__ __align__(16) u16 Bs[128 * 32];
  const int tid = threadIdx.x;
  const int wid = tid >> 6;
  const int lane = tid & 63;
  const int m0 = blockIdx.x * 128;
  const int n0 = blockIdx.y * 128;

  const int srow = lane >> 2;         // staging: 16 rows per 1KB issue
  const int scol = (lane & 3) * 8;    // 4 lanes x 8 bf16 per row
  const int wm = (wid >> 1) * 64;     // compute: wave -> 64x64 subtile
  const int wn = (wid & 1) * 64;
  const int fr = lane & 15;
  const int fk = (lane >> 4) * 8;

  f32x4 acc[4][4];
#pragma unroll
  for (int i = 0; i < 4; ++i)
#pragma unroll
    for (int j = 0; j < 4; ++j) acc[i][j] = (f32x4){0.f, 0.f, 0.f, 0.f};

  for (int k0 = 0; k0 < KPAD; k0 += 32) {
    __syncthreads();
#pragma unroll
    for (int i = 0; i < 2; ++i) {
      int ar = wid * 32 + i * 16;
      int gm = m0 + ar + srow;
      if (gm >= M) gm = M - 1;
      gload_lds16(A + (size_t)gm * KPAD + k0 + scol, As + ar * 32);
      int gn = n0 + ar + srow;
      gload_lds16(B + (size_t)gn * KPAD + k0 + scol, Bs + ar * 32);
    }
    __syncthreads();
    bf16x8 af[4], bfr[4];
#pragma unroll
    for (int r = 0; r < 4; ++r)
      af[r] = *(const bf16x8*)(As + (wm + r * 16 + fr) * 32 + fk);
#pragma unroll
    for (int c = 0; c < 4; ++c)
      bfr[c] = *(const bf16x8*)(Bs + (wn + c * 16 + fr) * 32 + fk);
#pragma unroll
    for (int r = 0; r < 4; ++r)
#pragma unroll
      for (int c = 0; c < 4; ++c)
        acc[r][c] = __builtin_amdgcn_mfma_f32_16x16x32_bf16(af[r], bfr[c],
                                                            acc[r][c], 0, 0, 0);
  }

  const int cr = (lane >> 4) * 4;
#pragma unroll
  for (int c = 0; c < 4; ++c) {
    int gcol = n0 + wn + c * 16 + fr;
    float bv = bias[gcol];
#pragma unroll
    for (int r = 0; r < 4; ++r) {
#pragma unroll
      for (int j = 0; j < 4; ++j) {
        int gm = m0 + wm + r * 16 + cr + j;
        if (gm < M) {
          float v = acc[r][c][j] + bv;
          if (RELU) v = fmaxf(v, 0.f);
          if (OUT_BF16)
            ((u16*)Cout)[(size_t)gm * OUTC + gcol] = f32_to_bf16(v);
          else
            ((float*)Cout)[(size_t)gm * OUTC + gcol] = v;
        }
      }
    }
  }
}

// ---------------- row L2 normalize in place ----------------
__global__ __launch_bounds__(256) void norm_rows(float* __restrict__ o) {
  __shared__ float wsum[4];
  int r = blockIdx.x;
  int tid = threadIdx.x;
  float2 v = *(float2*)(o + (size_t)r * OUTC + tid * 2);
  float ss = v.x * v.x + v.y * v.y;
#pragma unroll
  for (int off = 32; off > 0; off >>= 1) ss += __shfl_xor(ss, off, 64);
  if ((tid & 63) == 0) wsum[tid >> 6] = ss;
  __syncthreads();
  float tot = wsum[0] + wsum[1] + wsum[2] + wsum[3];
  float inv = 1.0f / fmaxf(sqrtf(tot), 1e-12f);
  v.x *= inv;
  v.y *= inv;
  *(float2*)(o + (size_t)r * OUTC + tid * 2) = v;
}

extern "C" void kernel_launch(void* const* d_in, const int* in_sizes, int n_in,
                              void* d_out, int out_size, void* d_ws,
                              size_t ws_size, hipStream_t stream) {
  const float* x  = (const float*)d_in[0];
  const int* erow = (const int*)d_in[1];
  const int* ecol = (const int*)d_in[2];
  const float* ev = (const float*)d_in[3];
  const float* W1 = (const float*)d_in[4];
  const float* b1 = (const float*)d_in[5];
  const float* W2 = (const float*)d_in[6];
  const float* b2 = (const float*)d_in[7];
  const int E = in_sizes[1];

  char* p = (char*)d_ws;
  auto carve = [&](size_t bytes) {
    char* q = p;
    p += (bytes + 255) & ~(size_t)255;
    return q;
  };
  u16* ax  = (u16*)carve((size_t)N_NODES * KP1 * 2);   // 32 MB
  u16* h   = (u16*)carve((size_t)N_NODES * HID * 2);   // 51.2 MB
  u16* ah  = (u16*)carve((size_t)N_NODES * HID * 2);   // 51.2 MB
  u16* W1b = (u16*)carve((size_t)HID * KP1 * 2);
  u16* W2b = (u16*)carve((size_t)OUTC * HID * 2);
  int* deg  = (int*)carve((size_t)N_NODES * 4);
  int* rs   = (int*)carve((size_t)(N_NODES + 1) * 4);
  int* cur  = (int*)carve((size_t)N_NODES * 4);
  int* perm = (int*)carve((size_t)E * 4);

  hipMemsetAsync(deg, 0, (size_t)N_NODES * 4, stream);
  hipMemsetAsync(cur, 0, (size_t)N_NODES * 4, stream);

  int eb = (E + 255) / 256;
  k_hist<<<eb, 256, 0, stream>>>(erow, E, deg);
  k_scan<<<1, 1024, 0, stream>>>(deg, rs);
  k_scatter<<<eb, 256, 0, stream>>>(erow, E, rs, cur, perm);

  k_convw<<<(HID * KP1 + 255) / 256, 256, 0, stream>>>(W1, W1b, INC, KP1, HID * KP1);
  k_convw<<<(OUTC * HID + 255) / 256, 256, 0, stream>>>(W2, W2b, HID, HID, OUTC * HID);

  // layer 1: (A @ x) @ W1^T + b1, relu  -> h (bf16)
  spmm_x<<<N_NODES, 256, 0, stream>>>(x, ecol, ev, perm, rs, ax);
  dim3 g1((N_NODES + 127) / 128, OUTC / 128);
  gemm_nt<KP1, true, true><<<g1, 256, 0, stream>>>(ax, W1b, b1, h, N_NODES);

  // layer 2: (A @ h) @ W2^T + b2 -> d_out (f32), then row-normalize
  spmm_h<<<N_NODES, 256, 0, stream>>>(h, ecol, ev, perm, rs, ah);
  gemm_nt<HID, false, false><<<g1, 256, 0, stream>>>(ah, W2b, b2, d_out, N_NODES);
  norm_rows<<<N_NODES, 256, 0, stream>>>((float*)d_out);
}

// Round 2
// 553.656 us; speedup vs baseline: 1.5862x; 1.5862x over previous
//
#include <hip/hip_runtime.h>

#define N_NODES 50000
#define INC 300
#define KP1 320      // padded K for layer-1 GEMM
#define HID 512
#define OUTC 512

typedef unsigned short u16;
typedef __bf16 bf16;
typedef bf16 bf16x8 __attribute__((ext_vector_type(8)));
typedef float f32x4 __attribute__((ext_vector_type(4)));

__device__ inline u16 f32_to_bf16(float f) {
  unsigned u = __float_as_uint(f);
  u += 0x7FFFu + ((u >> 16) & 1u);   // round-to-nearest-even
  return (u16)(u >> 16);
}

__device__ inline float bf_lo(unsigned u) { return __uint_as_float(u << 16); }
__device__ inline float bf_hi(unsigned u) { return __uint_as_float(u & 0xFFFF0000u); }

__device__ inline void gload_lds16(const void* g, void* l) {
  __builtin_amdgcn_global_load_lds(
      (const __attribute__((address_space(1))) void*)g,
      (__attribute__((address_space(3))) void*)l, 16, 0, 0);
}

// ---------------- CSR build ----------------
__global__ void k_hist(const int* __restrict__ erow, int E, int* __restrict__ deg) {
  int i = blockIdx.x * blockDim.x + threadIdx.x;
  if (i < E) atomicAdd(&deg[erow[i]], 1);
}

__global__ __launch_bounds__(1024) void k_scan(const int* __restrict__ deg,
                                               int* __restrict__ rowstart) {
  __shared__ int part[1024];
  int tid = threadIdx.x;
  const int ch = (N_NODES + 1023) / 1024;
  int lo = tid * ch;
  int hi = lo + ch;
  if (lo > N_NODES) lo = N_NODES;
  if (hi > N_NODES) hi = N_NODES;
  int s = 0;
  for (int i = lo; i < hi; ++i) s += deg[i];
  part[tid] = s;
  __syncthreads();
  for (int off = 1; off < 1024; off <<= 1) {
    int v = (tid >= off) ? part[tid - off] : 0;
    __syncthreads();
    part[tid] += v;
    __syncthreads();
  }
  int run = (tid > 0) ? part[tid - 1] : 0;
  for (int i = lo; i < hi; ++i) { rowstart[i] = run; run += deg[i]; }
  if (tid == 1023) rowstart[N_NODES] = part[1023];
}

// scatter edge data into CSR order (removes perm indirection from hot loops)
__global__ void k_scatter(const int* __restrict__ erow, const int* __restrict__ ecol,
                          const float* __restrict__ ev, int E,
                          const int* __restrict__ rowstart,
                          int* __restrict__ cursor,
                          int* __restrict__ csr_col, float* __restrict__ csr_val) {
  int i = blockIdx.x * blockDim.x + threadIdx.x;
  if (i < E) {
    int r = erow[i];
    int p = atomicAdd(&cursor[r], 1);
    int o = rowstart[r] + p;
    csr_col[o] = ecol[i];
    csr_val[o] = ev[i];
  }
}

// ---------------- weight f32 -> bf16 (zero-padded K) ----------------
__global__ void k_convw(const float* __restrict__ W, u16* __restrict__ Wb,
                        int K, int KPADc, int total) {
  int i = blockIdx.x * blockDim.x + threadIdx.x;
  if (i < total) {
    int r = i / KPADc, k = i - r * KPADc;
    Wb[i] = (k < K) ? f32_to_bf16(W[(size_t)r * K + k]) : (u16)0;
  }
}

// ---------------- x f32[N,300] -> bf16 packed u32 [N,160] (zero-padded) -------
__global__ __launch_bounds__(256) void k_convx(const float* __restrict__ x,
                                               unsigned* __restrict__ xb) {
  int i = blockIdx.x * blockDim.x + threadIdx.x;     // over N*160 u32 slots
  if (i >= N_NODES * 160) return;
  int r = i / 160, j = i - r * 160;
  unsigned out = 0;
  if (2 * j < INC) {
    float2 v = *(const float2*)(x + (size_t)r * INC + 2 * j);
    out = (unsigned)f32_to_bf16(v.x) | ((unsigned)f32_to_bf16(v.y) << 16);
  }
  xb[i] = out;
}

// ---------------- SpMM layer 1: ax = A @ xb  (bf16 gather, 4-deep pipelined) --
__global__ __launch_bounds__(192) void spmm_x(
    const unsigned* __restrict__ xb, const int* __restrict__ csr_col,
    const float* __restrict__ csr_val, const int* __restrict__ rs,
    unsigned* __restrict__ ax) {
  int r = blockIdx.x;
  int tid = threadIdx.x;
  if (tid >= 160) return;                 // 320 bf16 = 160 u32 per row
  int s = rs[r], e = rs[r + 1];
  float a0 = 0.f, a1 = 0.f, a2 = 0.f, a3 = 0.f;
  int i = s;
  for (; i + 4 <= e; i += 4) {
    int c0 = csr_col[i], c1 = csr_col[i + 1], c2 = csr_col[i + 2], c3 = csr_col[i + 3];
    float v0 = csr_val[i], v1 = csr_val[i + 1], v2 = csr_val[i + 2], v3 = csr_val[i + 3];
    unsigned q0 = xb[(size_t)c0 * 160 + tid];
    unsigned q1 = xb[(size_t)c1 * 160 + tid];
    unsigned q2 = xb[(size_t)c2 * 160 + tid];
    unsigned q3 = xb[(size_t)c3 * 160 + tid];
    a0 += v0 * bf_lo(q0); a1 += v0 * bf_hi(q0);
    a2 += v1 * bf_lo(q1); a3 += v1 * bf_hi(q1);
    a0 += v2 * bf_lo(q2); a1 += v2 * bf_hi(q2);
    a2 += v3 * bf_lo(q3); a3 += v3 * bf_hi(q3);
  }
  for (; i < e; ++i) {
    int c = csr_col[i];
    float v = csr_val[i];
    unsigned q = xb[(size_t)c * 160 + tid];
    a0 += v * bf_lo(q); a1 += v * bf_hi(q);
  }
  a0 += a2; a1 += a3;
  unsigned o0 = f32_to_bf16(a0);
  unsigned o1 = f32_to_bf16(a1);
  ax[(size_t)r * 160 + tid] = o0 | (o1 << 16);
}

// ---------------- SpMM layer 2: ah = A @ h   (bf16, 512 wide, pipelined) ------
__global__ __launch_bounds__(256) void spmm_h(
    const unsigned* __restrict__ h, const int* __restrict__ csr_col,
    const float* __restrict__ csr_val, const int* __restrict__ rs,
    unsigned* __restrict__ ah) {
  int r = blockIdx.x;
  int tid = threadIdx.x;                  // 512 bf16 = 256 u32 per row
  int s = rs[r], e = rs[r + 1];
  float a0 = 0.f, a1 = 0.f, a2 = 0.f, a3 = 0.f;
  int i = s;
  for (; i + 4 <= e; i += 4) {
    int c0 = csr_col[i], c1 = csr_col[i + 1], c2 = csr_col[i + 2], c3 = csr_col[i + 3];
    float v0 = csr_val[i], v1 = csr_val[i + 1], v2 = csr_val[i + 2], v3 = csr_val[i + 3];
    unsigned q0 = h[(size_t)c0 * 256 + tid];
    unsigned q1 = h[(size_t)c1 * 256 + tid];
    unsigned q2 = h[(size_t)c2 * 256 + tid];
    unsigned q3 = h[(size_t)c3 * 256 + tid];
    a0 += v0 * bf_lo(q0); a1 += v0 * bf_hi(q0);
    a2 += v1 * bf_lo(q1); a3 += v1 * bf_hi(q1);
    a0 += v2 * bf_lo(q2); a1 += v2 * bf_hi(q2);
    a2 += v3 * bf_lo(q3); a3 += v3 * bf_hi(q3);
  }
  for (; i < e; ++i) {
    int c = csr_col[i];
    float v = csr_val[i];
    unsigned q = h[(size_t)c * 256 + tid];
    a0 += v * bf_lo(q); a1 += v * bf_hi(q);
  }
  a0 += a2; a1 += a3;
  unsigned o0 = f32_to_bf16(a0);
  unsigned o1 = f32_to_bf16(a1);
  ah[(size_t)r * 256 + tid] = o0 | (o1 << 16);
}

// ---------------- bf16 MFMA GEMM:  C[M,512] = A[M,KPAD] @ B[512,KPAD]^T + bias -
template <int KPAD, bool RELU, bool OUT_BF16>
__global__ __launch_bounds__(256) void gemm_nt(
    const u16* __restrict__ A, const u16* __restrict__ B,
    const float* __restrict__ bias, void* __restrict__ Cout, int M) {
  __shared__ __align__(16) u16 As[128 * 32];
  __shared__ __align__(16) u16 Bs[128 * 32];
  const int tid = threadIdx.x;
  const int wid = tid >> 6;
  const int lane = tid & 63;
  const int m0 = blockIdx.x * 128;
  const int n0 = blockIdx.y * 128;

  const int srow = lane >> 2;
  const int scol = (lane & 3) * 8;
  const int wm = (wid >> 1) * 64;
  const int wn = (wid & 1) * 64;
  const int fr = lane & 15;
  const int fk = (lane >> 4) * 8;

  f32x4 acc[4][4];
#pragma unroll
  for (int i = 0; i < 4; ++i)
#pragma unroll
    for (int j = 0; j < 4; ++j) acc[i][j] = (f32x4){0.f, 0.f, 0.f, 0.f};

  for (int k0 = 0; k0 < KPAD; k0 += 32) {
    __syncthreads();
#pragma unroll
    for (int i = 0; i < 2; ++i) {
      int ar = wid * 32 + i * 16;
      int gm = m0 + ar + srow;
      if (gm >= M) gm = M - 1;
      gload_lds16(A + (size_t)gm * KPAD + k0 + scol, As + ar * 32);
      int gn = n0 + ar + srow;
      gload_lds16(B + (size_t)gn * KPAD + k0 + scol, Bs + ar * 32);
    }
    __syncthreads();
    bf16x8 af[4], bfr[4];
#pragma unroll
    for (int r = 0; r < 4; ++r)
      af[r] = *(const bf16x8*)(As + (wm + r * 16 + fr) * 32 + fk);
#pragma unroll
    for (int c = 0; c < 4; ++c)
      bfr[c] = *(const bf16x8*)(Bs + (wn + c * 16 + fr) * 32 + fk);
#pragma unroll
    for (int r = 0; r < 4; ++r)
#pragma unroll
      for (int c = 0; c < 4; ++c)
        acc[r][c] = __builtin_amdgcn_mfma_f32_16x16x32_bf16(af[r], bfr[c],
                                                            acc[r][c], 0, 0, 0);
  }

  const int cr = (lane >> 4) * 4;
#pragma unroll
  for (int c = 0; c < 4; ++c) {
    int gcol = n0 + wn + c * 16 + fr;
    float bv = bias[gcol];
#pragma unroll
    for (int r = 0; r < 4; ++r) {
#pragma unroll
      for (int j = 0; j < 4; ++j) {
        int gm = m0 + wm + r * 16 + cr + j;
        if (gm < M) {
          float v = acc[r][c][j] + bv;
          if (RELU) v = fmaxf(v, 0.f);
          if (OUT_BF16)
            ((u16*)Cout)[(size_t)gm * OUTC + gcol] = f32_to_bf16(v);
          else
            ((float*)Cout)[(size_t)gm * OUTC + gcol] = v;
        }
      }
    }
  }
}

// ---------------- row L2 normalize in place ----------------
__global__ __launch_bounds__(256) void norm_rows(float* __restrict__ o) {
  __shared__ float wsum[4];
  int r = blockIdx.x;
  int tid = threadIdx.x;
  float2 v = *(float2*)(o + (size_t)r * OUTC + tid * 2);
  float ss = v.x * v.x + v.y * v.y;
#pragma unroll
  for (int off = 32; off > 0; off >>= 1) ss += __shfl_xor(ss, off, 64);
  if ((tid & 63) == 0) wsum[tid >> 6] = ss;
  __syncthreads();
  float tot = wsum[0] + wsum[1] + wsum[2] + wsum[3];
  float inv = 1.0f / fmaxf(sqrtf(tot), 1e-12f);
  v.x *= inv;
  v.y *= inv;
  *(float2*)(o + (size_t)r * OUTC + tid * 2) = v;
}

extern "C" void kernel_launch(void* const* d_in, const int* in_sizes, int n_in,
                              void* d_out, int out_size, void* d_ws,
                              size_t ws_size, hipStream_t stream) {
  const float* x  = (const float*)d_in[0];
  const int* erow = (const int*)d_in[1];
  const int* ecol = (const int*)d_in[2];
  const float* ev = (const float*)d_in[3];
  const float* W1 = (const float*)d_in[4];
  const float* b1 = (const float*)d_in[5];
  const float* W2 = (const float*)d_in[6];
  const float* b2 = (const float*)d_in[7];
  const int E = in_sizes[1];

  char* p = (char*)d_ws;
  auto carve = [&](size_t bytes) {
    char* q = p;
    p += (bytes + 255) & ~(size_t)255;
    return q;
  };
  unsigned* xb = (unsigned*)carve((size_t)N_NODES * 160 * 4);  // 32 MB bf16 x
  unsigned* ax = (unsigned*)carve((size_t)N_NODES * 160 * 4);  // 32 MB
  unsigned* h  = (unsigned*)carve((size_t)N_NODES * 256 * 4);  // 51.2 MB
  unsigned* ah = (unsigned*)carve((size_t)N_NODES * 256 * 4);  // 51.2 MB
  u16* W1b = (u16*)carve((size_t)HID * KP1 * 2);
  u16* W2b = (u16*)carve((size_t)OUTC * HID * 2);
  int* deg  = (int*)carve((size_t)N_NODES * 4);
  int* rs   = (int*)carve((size_t)(N_NODES + 1) * 4);
  int* cur  = (int*)carve((size_t)N_NODES * 4);
  int* csr_col = (int*)carve((size_t)E * 4);
  float* csr_val = (float*)carve((size_t)E * 4);

  hipMemsetAsync(deg, 0, (size_t)N_NODES * 4, stream);
  hipMemsetAsync(cur, 0, (size_t)N_NODES * 4, stream);

  int eb = (E + 255) / 256;
  k_hist<<<eb, 256, 0, stream>>>(erow, E, deg);
  k_scan<<<1, 1024, 0, stream>>>(deg, rs);
  k_scatter<<<eb, 256, 0, stream>>>(erow, ecol, ev, E, rs, cur, csr_col, csr_val);

  k_convx<<<(N_NODES * 160 + 255) / 256, 256, 0, stream>>>(x, xb);
  k_convw<<<(HID * KP1 + 255) / 256, 256, 0, stream>>>(W1, W1b, INC, KP1, HID * KP1);
  k_convw<<<(OUTC * HID + 255) / 256, 256, 0, stream>>>(W2, W2b, HID, HID, OUTC * HID);

  // layer 1: (A @ x) @ W1^T + b1, relu  -> h (bf16)
  spmm_x<<<N_NODES, 192, 0, stream>>>(xb, csr_col, csr_val, rs, ax);
  dim3 g1((N_NODES + 127) / 128, OUTC / 128);
  gemm_nt<KP1, true, true><<<g1, 256, 0, stream>>>((const u16*)ax, W1b, b1, h, N_NODES);

  // layer 2: (A @ h) @ W2^T + b2 -> d_out (f32), then row-normalize
  spmm_h<<<N_NODES, 256, 0, stream>>>(h, csr_col, csr_val, rs, ah);
  gemm_nt<HID, false, false><<<g1, 256, 0, stream>>>((const u16*)ah, W2b, b2, d_out, N_NODES);
  norm_rows<<<N_NODES, 256, 0, stream>>>((float*)d_out);
}

// Round 3
// 492.993 us; speedup vs baseline: 1.7814x; 1.1231x over previous
//
#include <hip/hip_runtime.h>

#define N_NODES 50000
#define INC 300
#define KP1 320      // padded K for layer-1 GEMM (bf16)
#define HID 512
#define OUTC 512

typedef unsigned short u16;
typedef __bf16 bf16;
typedef bf16 bf16x8 __attribute__((ext_vector_type(8)));
typedef float f32x4 __attribute__((ext_vector_type(4)));
typedef unsigned u32x4 __attribute__((ext_vector_type(4)));

__device__ inline u16 f32_to_bf16(float f) {
  unsigned u = __float_as_uint(f);
  u += 0x7FFFu + ((u >> 16) & 1u);   // round-to-nearest-even
  return (u16)(u >> 16);
}

__device__ inline float bf_lo(unsigned u) { return __uint_as_float(u << 16); }
__device__ inline float bf_hi(unsigned u) { return __uint_as_float(u & 0xFFFF0000u); }

__device__ inline void gload_lds16(const void* g, void* l) {
  __builtin_amdgcn_global_load_lds(
      (const __attribute__((address_space(1))) void*)g,
      (__attribute__((address_space(3))) void*)l, 16, 0, 0);
}

// ---------------- CSR build ----------------
__global__ void k_hist(const int* __restrict__ erow, int E, int* __restrict__ deg) {
  int i = blockIdx.x * blockDim.x + threadIdx.x;
  if (i < E) atomicAdd(&deg[erow[i]], 1);
}

__global__ __launch_bounds__(1024) void k_scan(const int* __restrict__ deg,
                                               int* __restrict__ rowstart) {
  __shared__ int part[1024];
  int tid = threadIdx.x;
  const int ch = (N_NODES + 1023) / 1024;
  int lo = tid * ch;
  int hi = lo + ch;
  if (lo > N_NODES) lo = N_NODES;
  if (hi > N_NODES) hi = N_NODES;
  int s = 0;
  for (int i = lo; i < hi; ++i) s += deg[i];
  part[tid] = s;
  __syncthreads();
  for (int off = 1; off < 1024; off <<= 1) {
    int v = (tid >= off) ? part[tid - off] : 0;
    __syncthreads();
    part[tid] += v;
    __syncthreads();
  }
  int run = (tid > 0) ? part[tid - 1] : 0;
  for (int i = lo; i < hi; ++i) { rowstart[i] = run; run += deg[i]; }
  if (tid == 1023) rowstart[N_NODES] = part[1023];
}

// scatter cols into CSR order (vals are 1/deg(row) -> applied per row later)
__global__ void k_scatter(const int* __restrict__ erow, const int* __restrict__ ecol,
                          int E, const int* __restrict__ rowstart,
                          int* __restrict__ cursor, int* __restrict__ csr_col) {
  int i = blockIdx.x * blockDim.x + threadIdx.x;
  if (i < E) {
    int r = erow[i];
    int p = atomicAdd(&cursor[r], 1);
    csr_col[rowstart[r] + p] = ecol[i];
  }
}

// ---------------- weight f32 -> bf16 (zero-padded K) ----------------
__global__ void k_convw(const float* __restrict__ W, u16* __restrict__ Wb,
                        int K, int KPADc, int total) {
  int i = blockIdx.x * blockDim.x + threadIdx.x;
  if (i < total) {
    int r = i / KPADc, k = i - r * KPADc;
    Wb[i] = (k < K) ? f32_to_bf16(W[(size_t)r * K + k]) : (u16)0;
  }
}

// ---------------- x f32[N,300] -> bf16 packed u32 [N,160] (zero-padded) -------
__global__ __launch_bounds__(256) void k_convx(const float* __restrict__ x,
                                               unsigned* __restrict__ xb) {
  int i = blockIdx.x * blockDim.x + threadIdx.x;     // over N*160 u32 slots
  if (i >= N_NODES * 160) return;
  int r = i / 160, j = i - r * 160;
  unsigned out = 0;
  if (2 * j < INC) {
    float2 v = *(const float2*)(x + (size_t)r * INC + 2 * j);
    out = (unsigned)f32_to_bf16(v.x) | ((unsigned)f32_to_bf16(v.y) << 16);
  }
  xb[i] = out;
}

// ---------------- SpMM layer 1: ax = A @ xb  (wave-per-row, dwordx4 gather) ---
// row = 160 u32 = 40 lanes x u32x4; lanes 40..63 idle (memory-bound kernel)
__global__ __launch_bounds__(256) void spmm_x(
    const u32x4* __restrict__ xb, const int* __restrict__ csr_col,
    const int* __restrict__ rs, u32x4* __restrict__ ax) {
  int r = blockIdx.x * 4 + (threadIdx.x >> 6);
  int lane = threadIdx.x & 63;
  if (lane >= 40) return;
  int s = rs[r], e = rs[r + 1];
  float a[8];
#pragma unroll
  for (int k = 0; k < 8; ++k) a[k] = 0.f;
  int i = s;
  for (; i + 4 <= e; i += 4) {
    int c0 = csr_col[i], c1 = csr_col[i + 1], c2 = csr_col[i + 2], c3 = csr_col[i + 3];
    u32x4 q0 = xb[(size_t)c0 * 40 + lane];
    u32x4 q1 = xb[(size_t)c1 * 40 + lane];
    u32x4 q2 = xb[(size_t)c2 * 40 + lane];
    u32x4 q3 = xb[(size_t)c3 * 40 + lane];
#pragma unroll
    for (int j = 0; j < 4; ++j) {
      a[2 * j]     += bf_lo(q0[j]) + bf_lo(q1[j]) + bf_lo(q2[j]) + bf_lo(q3[j]);
      a[2 * j + 1] += bf_hi(q0[j]) + bf_hi(q1[j]) + bf_hi(q2[j]) + bf_hi(q3[j]);
    }
  }
  for (; i < e; ++i) {
    int c = csr_col[i];
    u32x4 q = xb[(size_t)c * 40 + lane];
#pragma unroll
    for (int j = 0; j < 4; ++j) {
      a[2 * j]     += bf_lo(q[j]);
      a[2 * j + 1] += bf_hi(q[j]);
    }
  }
  float inv = 1.0f / (float)max(e - s, 1);
  u32x4 o;
#pragma unroll
  for (int j = 0; j < 4; ++j) {
    unsigned lo = f32_to_bf16(a[2 * j] * inv);
    unsigned hi = f32_to_bf16(a[2 * j + 1] * inv);
    o[j] = lo | (hi << 16);
  }
  ax[(size_t)r * 40 + lane] = o;
}

// ---- SpMM layer 2 fused: out = normalize( (A @ g) * (implicit 1/deg) + b2 ) --
// g rows: 256 u32 = 64 lanes x u32x4. Full row lives in one wave -> fuse norm.
__global__ __launch_bounds__(256) void spmm_norm(
    const u32x4* __restrict__ g, const int* __restrict__ csr_col,
    const int* __restrict__ rs, const float* __restrict__ b2,
    float* __restrict__ out) {
  int r = blockIdx.x * 4 + (threadIdx.x >> 6);
  int lane = threadIdx.x & 63;
  int s = rs[r], e = rs[r + 1];
  float a[8];
#pragma unroll
  for (int k = 0; k < 8; ++k) a[k] = 0.f;
  int i = s;
  for (; i + 4 <= e; i += 4) {
    int c0 = csr_col[i], c1 = csr_col[i + 1], c2 = csr_col[i + 2], c3 = csr_col[i + 3];
    u32x4 q0 = g[(size_t)c0 * 64 + lane];
    u32x4 q1 = g[(size_t)c1 * 64 + lane];
    u32x4 q2 = g[(size_t)c2 * 64 + lane];
    u32x4 q3 = g[(size_t)c3 * 64 + lane];
#pragma unroll
    for (int j = 0; j < 4; ++j) {
      a[2 * j]     += bf_lo(q0[j]) + bf_lo(q1[j]) + bf_lo(q2[j]) + bf_lo(q3[j]);
      a[2 * j + 1] += bf_hi(q0[j]) + bf_hi(q1[j]) + bf_hi(q2[j]) + bf_hi(q3[j]);
    }
  }
  for (; i < e; ++i) {
    int c = csr_col[i];
    u32x4 q = g[(size_t)c * 64 + lane];
#pragma unroll
    for (int j = 0; j < 4; ++j) {
      a[2 * j]     += bf_lo(q[j]);
      a[2 * j + 1] += bf_hi(q[j]);
    }
  }
  float inv = 1.0f / (float)max(e - s, 1);
  float4 bv0 = *(const float4*)(b2 + lane * 8);
  float4 bv1 = *(const float4*)(b2 + lane * 8 + 4);
  float v[8];
  v[0] = a[0] * inv + bv0.x; v[1] = a[1] * inv + bv0.y;
  v[2] = a[2] * inv + bv0.z; v[3] = a[3] * inv + bv0.w;
  v[4] = a[4] * inv + bv1.x; v[5] = a[5] * inv + bv1.y;
  v[6] = a[6] * inv + bv1.z; v[7] = a[7] * inv + bv1.w;
  float ss = 0.f;
#pragma unroll
  for (int k = 0; k < 8; ++k) ss += v[k] * v[k];
#pragma unroll
  for (int off = 32; off > 0; off >>= 1) ss += __shfl_xor(ss, off, 64);
  float innrm = 1.0f / fmaxf(sqrtf(ss), 1e-12f);
  float4 o0 = {v[0] * innrm, v[1] * innrm, v[2] * innrm, v[3] * innrm};
  float4 o1 = {v[4] * innrm, v[5] * innrm, v[6] * innrm, v[7] * innrm};
  float* op = out + (size_t)r * OUTC + lane * 8;
  *(float4*)op = o0;
  *(float4*)(op + 4) = o1;
}

// ---------------- bf16 MFMA GEMM:  C[M,512] = A[M,KPAD] @ B[512,KPAD]^T (+bias)
template <int KPAD, bool RELU, bool HAS_BIAS>
__global__ __launch_bounds__(256) void gemm_nt(
    const u16* __restrict__ A, const u16* __restrict__ B,
    const float* __restrict__ bias, u16* __restrict__ Cout, int M) {
  __shared__ __align__(16) u16 As[128 * 32];
  __shared__ __align__(16) u16 Bs[128 * 32];
  const int tid = threadIdx.x;
  const int wid = tid >> 6;
  const int lane = tid & 63;
  const int m0 = blockIdx.x * 128;
  const int n0 = blockIdx.y * 128;

  const int srow = lane >> 2;
  const int scol = (lane & 3) * 8;
  const int wm = (wid >> 1) * 64;
  const int wn = (wid & 1) * 64;
  const int fr = lane & 15;
  const int fk = (lane >> 4) * 8;

  f32x4 acc[4][4];
#pragma unroll
  for (int i = 0; i < 4; ++i)
#pragma unroll
    for (int j = 0; j < 4; ++j) acc[i][j] = (f32x4){0.f, 0.f, 0.f, 0.f};

  for (int k0 = 0; k0 < KPAD; k0 += 32) {
    __syncthreads();
#pragma unroll
    for (int i = 0; i < 2; ++i) {
      int ar = wid * 32 + i * 16;
      int gm = m0 + ar + srow;
      if (gm >= M) gm = M - 1;
      gload_lds16(A + (size_t)gm * KPAD + k0 + scol, As + ar * 32);
      int gn = n0 + ar + srow;
      gload_lds16(B + (size_t)gn * KPAD + k0 + scol, Bs + ar * 32);
    }
    __syncthreads();
    bf16x8 af[4], bfr[4];
#pragma unroll
    for (int r = 0; r < 4; ++r)
      af[r] = *(const bf16x8*)(As + (wm + r * 16 + fr) * 32 + fk);
#pragma unroll
    for (int c = 0; c < 4; ++c)
      bfr[c] = *(const bf16x8*)(Bs + (wn + c * 16 + fr) * 32 + fk);
#pragma unroll
    for (int r = 0; r < 4; ++r)
#pragma unroll
      for (int c = 0; c < 4; ++c)
        acc[r][c] = __builtin_amdgcn_mfma_f32_16x16x32_bf16(af[r], bfr[c],
                                                            acc[r][c], 0, 0, 0);
  }

  const int cr = (lane >> 4) * 4;
#pragma unroll
  for (int c = 0; c < 4; ++c) {
    int gcol = n0 + wn + c * 16 + fr;
    float bv = HAS_BIAS ? bias[gcol] : 0.f;
#pragma unroll
    for (int r = 0; r < 4; ++r) {
#pragma unroll
      for (int j = 0; j < 4; ++j) {
        int gm = m0 + wm + r * 16 + cr + j;
        if (gm < M) {
          float v = acc[r][c][j] + bv;
          if (RELU) v = fmaxf(v, 0.f);
          Cout[(size_t)gm * OUTC + gcol] = f32_to_bf16(v);
        }
      }
    }
  }
}

extern "C" void kernel_launch(void* const* d_in, const int* in_sizes, int n_in,
                              void* d_out, int out_size, void* d_ws,
                              size_t ws_size, hipStream_t stream) {
  const float* x  = (const float*)d_in[0];
  const int* erow = (const int*)d_in[1];
  const int* ecol = (const int*)d_in[2];
  const float* W1 = (const float*)d_in[4];
  const float* b1 = (const float*)d_in[5];
  const float* W2 = (const float*)d_in[6];
  const float* b2 = (const float*)d_in[7];
  const int E = in_sizes[1];

  char* p = (char*)d_ws;
  auto carve = [&](size_t bytes) {
    char* q = p;
    p += (bytes + 255) & ~(size_t)255;
    return q;
  };
  unsigned* xb = (unsigned*)carve((size_t)N_NODES * 160 * 4);  // 32 MB bf16 x
  unsigned* ax = (unsigned*)carve((size_t)N_NODES * 160 * 4);  // 32 MB
  unsigned* h  = (unsigned*)carve((size_t)N_NODES * 256 * 4);  // 51.2 MB
  unsigned* g2 = (unsigned*)carve((size_t)N_NODES * 256 * 4);  // 51.2 MB
  u16* W1b = (u16*)carve((size_t)HID * KP1 * 2);
  u16* W2b = (u16*)carve((size_t)OUTC * HID * 2);
  int* deg  = (int*)carve((size_t)N_NODES * 4);
  int* rs   = (int*)carve((size_t)(N_NODES + 1) * 4);
  int* cur  = (int*)carve((size_t)N_NODES * 4);
  int* csr_col = (int*)carve((size_t)E * 4);

  hipMemsetAsync(deg, 0, (size_t)N_NODES * 4, stream);
  hipMemsetAsync(cur, 0, (size_t)N_NODES * 4, stream);

  int eb = (E + 255) / 256;
  k_hist<<<eb, 256, 0, stream>>>(erow, E, deg);
  k_scan<<<1, 1024, 0, stream>>>(deg, rs);
  k_scatter<<<eb, 256, 0, stream>>>(erow, ecol, E, rs, cur, csr_col);

  k_convx<<<(N_NODES * 160 + 255) / 256, 256, 0, stream>>>(x, xb);
  k_convw<<<(HID * KP1 + 255) / 256, 256, 0, stream>>>(W1, W1b, INC, KP1, HID * KP1);
  k_convw<<<(OUTC * HID + 255) / 256, 256, 0, stream>>>(W2, W2b, HID, HID, OUTC * HID);

  dim3 g1((N_NODES + 127) / 128, OUTC / 128);
  // layer 1: h = relu((A @ x) @ W1^T + b1)
  spmm_x<<<N_NODES / 4, 256, 0, stream>>>((const u32x4*)xb, csr_col, rs, (u32x4*)ax);
  gemm_nt<KP1, true, true><<<g1, 256, 0, stream>>>((const u16*)ax, W1b, b1, (u16*)h, N_NODES);

  // layer 2: out = normalize(A @ (h @ W2^T) + b2)
  gemm_nt<HID, false, false><<<g1, 256, 0, stream>>>((const u16*)h, W2b, nullptr, (u16*)g2, N_NODES);
  spmm_norm<<<N_NODES / 4, 256, 0, stream>>>((const u32x4*)g2, csr_col, rs, b2, (float*)d_out);
}

// Round 5
// 467.974 us; speedup vs baseline: 1.8766x; 1.0535x over previous
//
#include <hip/hip_runtime.h>

#define N_NODES 50000
#define INC 300
#define KP1 320      // padded K for layer-1 GEMM (bf16)
#define HID 512
#define OUTC 512
#define MTILES 391   // ceil(50000/128)
#define MCHUNK 49    // ceil(391/8) m-tiles per XCD

typedef unsigned short u16;
typedef __bf16 bf16;
typedef bf16 bf16x8 __attribute__((ext_vector_type(8)));
typedef float f32x4 __attribute__((ext_vector_type(4)));
typedef float f32x2 __attribute__((ext_vector_type(2)));
typedef unsigned u32x4 __attribute__((ext_vector_type(4)));

__device__ inline u16 f32_to_bf16(float f) {
  unsigned u = __float_as_uint(f);
  u += 0x7FFFu + ((u >> 16) & 1u);   // round-to-nearest-even
  return (u16)(u >> 16);
}

__device__ inline float bf_lo(unsigned u) { return __uint_as_float(u << 16); }
__device__ inline float bf_hi(unsigned u) { return __uint_as_float(u & 0xFFFF0000u); }

__device__ inline void gload_lds16(const void* g, void* l) {
  __builtin_amdgcn_global_load_lds(
      (const __attribute__((address_space(1))) void*)g,
      (__attribute__((address_space(3))) void*)l, 16, 0, 0);
}

// ---------------- CSR build ----------------
__global__ void k_hist(const int* __restrict__ erow, int E, int* __restrict__ deg) {
  int i = blockIdx.x * blockDim.x + threadIdx.x;
  if (i < E) atomicAdd(&deg[erow[i]], 1);
}

__global__ __launch_bounds__(1024) void k_scan(const int* __restrict__ deg,
                                               int* __restrict__ rowstart) {
  __shared__ int part[1024];
  int tid = threadIdx.x;
  const int ch = (N_NODES + 1023) / 1024;
  int lo = tid * ch;
  int hi = lo + ch;
  if (lo > N_NODES) lo = N_NODES;
  if (hi > N_NODES) hi = N_NODES;
  int s = 0;
  for (int i = lo; i < hi; ++i) s += deg[i];
  part[tid] = s;
  __syncthreads();
  for (int off = 1; off < 1024; off <<= 1) {
    int v = (tid >= off) ? part[tid - off] : 0;
    __syncthreads();
    part[tid] += v;
    __syncthreads();
  }
  int run = (tid > 0) ? part[tid - 1] : 0;
  for (int i = lo; i < hi; ++i) { rowstart[i] = run; run += deg[i]; }
  if (tid == 1023) rowstart[N_NODES] = part[1023];
}

__global__ void k_scatter(const int* __restrict__ erow, const int* __restrict__ ecol,
                          int E, const int* __restrict__ rowstart,
                          int* __restrict__ cursor, int* __restrict__ csr_col) {
  int i = blockIdx.x * blockDim.x + threadIdx.x;
  if (i < E) {
    int r = erow[i];
    int p = atomicAdd(&cursor[r], 1);
    csr_col[rowstart[r] + p] = ecol[i];
  }
}

// ---------------- weight f32 -> bf16 (zero-padded K) ----------------
__global__ void k_convw(const float* __restrict__ W, u16* __restrict__ Wb,
                        int K, int KPADc, int total) {
  int i = blockIdx.x * blockDim.x + threadIdx.x;
  if (i < total) {
    int r = i / KPADc, k = i - r * KPADc;
    Wb[i] = (k < K) ? f32_to_bf16(W[(size_t)r * K + k]) : (u16)0;
  }
}

// ---------------- x f32[N,300] -> bf16 packed u32 [N,160] (zero-padded) -------
__global__ __launch_bounds__(256) void k_convx(const float* __restrict__ x,
                                               unsigned* __restrict__ xb) {
  int i = blockIdx.x * blockDim.x + threadIdx.x;     // over N*160 u32 slots
  if (i >= N_NODES * 160) return;
  int r = i / 160, j = i - r * 160;
  unsigned out = 0;
  if (2 * j < INC) {
    f32x2 v = __builtin_nontemporal_load((const f32x2*)(x + (size_t)r * INC + 2 * j));
    out = (unsigned)f32_to_bf16(v.x) | ((unsigned)f32_to_bf16(v.y) << 16);
  }
  xb[i] = out;
}

// ---------------- SpMM layer 1: ax = A @ xb  (wave/row, shfl-bcast cols) ------
// row = 160 u32 = 40 lanes x u32x4; lanes 40..63 alive (needed for shfl) but
// their gathers duplicate lane 39's line (coalesced away) and are not stored.
__global__ __launch_bounds__(256) void spmm_x(
    const u32x4* __restrict__ xb, const int* __restrict__ csr_col,
    const int* __restrict__ rs, u32x4* __restrict__ ax) {
  int r = blockIdx.x * 4 + (threadIdx.x >> 6);
  int lane = threadIdx.x & 63;
  int lanec = lane < 40 ? lane : 39;
  int s = rs[r], e = rs[r + 1];
  float a[8];
#pragma unroll
  for (int k = 0; k < 8; ++k) a[k] = 0.f;
  auto acc1 = [&](u32x4 q) {
#pragma unroll
    for (int t = 0; t < 4; ++t) {
      a[2 * t]     += bf_lo(q[t]);
      a[2 * t + 1] += bf_hi(q[t]);
    }
  };
  for (int base = s; base < e;) {
    int cnt = min(64, e - base);
    int myc = csr_col[base + min(lane, cnt - 1)];
    int j = 0;
    for (; j + 16 <= cnt; j += 16) {
      u32x4 q[16];
#pragma unroll
      for (int k = 0; k < 16; ++k) {
        int c = __shfl(myc, j + k, 64);
        q[k] = xb[(size_t)c * 40 + lanec];
      }
#pragma unroll
      for (int k = 0; k < 16; ++k) acc1(q[k]);
    }
    for (; j + 4 <= cnt; j += 4) {
      u32x4 q[4];
#pragma unroll
      for (int k = 0; k < 4; ++k) {
        int c = __shfl(myc, j + k, 64);
        q[k] = xb[(size_t)c * 40 + lanec];
      }
#pragma unroll
      for (int k = 0; k < 4; ++k) acc1(q[k]);
    }
    for (; j < cnt; ++j) {
      int c = __shfl(myc, j, 64);
      acc1(xb[(size_t)c * 40 + lanec]);
    }
    base += cnt;
  }
  float inv = 1.0f / (float)max(e - s, 1);
  u32x4 o;
#pragma unroll
  for (int j = 0; j < 4; ++j) {
    unsigned lo = f32_to_bf16(a[2 * j] * inv);
    unsigned hi = f32_to_bf16(a[2 * j + 1] * inv);
    o[j] = lo | (hi << 16);
  }
  if (lane < 40) ax[(size_t)r * 40 + lane] = o;
}

// ---- SpMM layer 2 fused: out = normalize( (A @ g) * 1/deg + b2 ) -------------
__global__ __launch_bounds__(256) void spmm_norm(
    const u32x4* __restrict__ g, const int* __restrict__ csr_col,
    const int* __restrict__ rs, const float* __restrict__ b2,
    float* __restrict__ out) {
  int r = blockIdx.x * 4 + (threadIdx.x >> 6);
  int lane = threadIdx.x & 63;
  int s = rs[r], e = rs[r + 1];
  float a[8];
#pragma unroll
  for (int k = 0; k < 8; ++k) a[k] = 0.f;
  auto acc1 = [&](u32x4 q) {
#pragma unroll
    for (int t = 0; t < 4; ++t) {
      a[2 * t]     += bf_lo(q[t]);
      a[2 * t + 1] += bf_hi(q[t]);
    }
  };
  for (int base = s; base < e;) {
    int cnt = min(64, e - base);
    int myc = csr_col[base + min(lane, cnt - 1)];
    int j = 0;
    for (; j + 16 <= cnt; j += 16) {
      u32x4 q[16];
#pragma unroll
      for (int k = 0; k < 16; ++k) {
        int c = __shfl(myc, j + k, 64);
        q[k] = g[(size_t)c * 64 + lane];
      }
#pragma unroll
      for (int k = 0; k < 16; ++k) acc1(q[k]);
    }
    for (; j + 4 <= cnt; j += 4) {
      u32x4 q[4];
#pragma unroll
      for (int k = 0; k < 4; ++k) {
        int c = __shfl(myc, j + k, 64);
        q[k] = g[(size_t)c * 64 + lane];
      }
#pragma unroll
      for (int k = 0; k < 4; ++k) acc1(q[k]);
    }
    for (; j < cnt; ++j) {
      int c = __shfl(myc, j, 64);
      acc1(g[(size_t)c * 64 + lane]);
    }
    base += cnt;
  }
  float inv = 1.0f / (float)max(e - s, 1);
  f32x4 bv0 = *(const f32x4*)(b2 + lane * 8);
  f32x4 bv1 = *(const f32x4*)(b2 + lane * 8 + 4);
  float v[8];
  v[0] = a[0] * inv + bv0.x; v[1] = a[1] * inv + bv0.y;
  v[2] = a[2] * inv + bv0.z; v[3] = a[3] * inv + bv0.w;
  v[4] = a[4] * inv + bv1.x; v[5] = a[5] * inv + bv1.y;
  v[6] = a[6] * inv + bv1.z; v[7] = a[7] * inv + bv1.w;
  float ss = 0.f;
#pragma unroll
  for (int k = 0; k < 8; ++k) ss += v[k] * v[k];
#pragma unroll
  for (int off = 32; off > 0; off >>= 1) ss += __shfl_xor(ss, off, 64);
  float innrm = 1.0f / fmaxf(sqrtf(ss), 1e-12f);
  f32x4 o0 = {v[0] * innrm, v[1] * innrm, v[2] * innrm, v[3] * innrm};
  f32x4 o1 = {v[4] * innrm, v[5] * innrm, v[6] * innrm, v[7] * innrm};
  float* op = out + (size_t)r * OUTC + lane * 8;
  __builtin_nontemporal_store(o0, (f32x4*)op);
  __builtin_nontemporal_store(o1, (f32x4*)(op + 4));
}

// ---- bf16 MFMA GEMM, XCD-grouped grid, double-buffered LDS prefetch ----------
// C[M,512] = A[M,KPAD] @ B[512,KPAD]^T (+bias, relu). Grid: 1568 1-D blocks;
// bid&7 = XCD, each XCD covers MCHUNK m-tiles x 4 n-tiles consecutively so the
// A-stripe stays in its private L2 across the 4 n-tiles.
template <int KPAD, bool RELU, bool HAS_BIAS>
__global__ __launch_bounds__(256) void gemm_nt(
    const u16* __restrict__ A, const u16* __restrict__ B,
    const float* __restrict__ bias, u16* __restrict__ Cout, int M) {
  __shared__ __align__(16) u16 AsB[2][128 * 32];
  __shared__ __align__(16) u16 BsB[2][128 * 32];
  const int bid = blockIdx.x;
  const int xcd = bid & 7;
  const int j = bid >> 3;
  const int mt = xcd * MCHUNK + (j >> 2);
  if (mt >= MTILES) return;
  const int m0 = mt * 128;
  const int n0 = (j & 3) * 128;

  const int tid = threadIdx.x;
  const int wid = tid >> 6;
  const int lane = tid & 63;

  const int srow = lane >> 2;
  const int scol = (lane & 3) * 8;
  const int wm = (wid >> 1) * 64;
  const int wn = (wid & 1) * 64;
  const int fr = lane & 15;
  const int fk = (lane >> 4) * 8;

  auto STAGE = [&](int buf, int k0) {
#pragma unroll
    for (int i = 0; i < 2; ++i) {
      int ar = wid * 32 + i * 16;
      int gm = m0 + ar + srow;
      if (gm >= M) gm = M - 1;
      gload_lds16(A + (size_t)gm * KPAD + k0 + scol, AsB[buf] + ar * 32);
      int gn = n0 + ar + srow;
      gload_lds16(B + (size_t)gn * KPAD + k0 + scol, BsB[buf] + ar * 32);
    }
  };

  f32x4 acc[4][4];
#pragma unroll
  for (int i = 0; i < 4; ++i)
#pragma unroll
    for (int jj = 0; jj < 4; ++jj) acc[i][jj] = (f32x4){0.f, 0.f, 0.f, 0.f};

  constexpr int NT = KPAD / 32;
  STAGE(0, 0);
  __syncthreads();
  int cur = 0;
  for (int t = 0; t < NT; ++t) {
    if (t + 1 < NT) STAGE(cur ^ 1, (t + 1) * 32);   // prefetch next tile
    const u16* As = AsB[cur];
    const u16* Bs = BsB[cur];
    bf16x8 af[4], bfr[4];
#pragma unroll
    for (int r = 0; r < 4; ++r)
      af[r] = *(const bf16x8*)(As + (wm + r * 16 + fr) * 32 + fk);
#pragma unroll
    for (int c = 0; c < 4; ++c)
      bfr[c] = *(const bf16x8*)(Bs + (wn + c * 16 + fr) * 32 + fk);
#pragma unroll
    for (int r = 0; r < 4; ++r)
#pragma unroll
      for (int c = 0; c < 4; ++c)
        acc[r][c] = __builtin_amdgcn_mfma_f32_16x16x32_bf16(af[r], bfr[c],
                                                            acc[r][c], 0, 0, 0);
    __syncthreads();   // drains STAGE vmcnt + this tile's ds_reads
    cur ^= 1;
  }

  const int cr = (lane >> 4) * 4;
#pragma unroll
  for (int c = 0; c < 4; ++c) {
    int gcol = n0 + wn + c * 16 + fr;
    float bv = HAS_BIAS ? bias[gcol] : 0.f;
#pragma unroll
    for (int r = 0; r < 4; ++r) {
#pragma unroll
      for (int jj = 0; jj < 4; ++jj) {
        int gm = m0 + wm + r * 16 + cr + jj;
        if (gm < M) {
          float v = acc[r][c][jj] + bv;
          if (RELU) v = fmaxf(v, 0.f);
          Cout[(size_t)gm * OUTC + gcol] = f32_to_bf16(v);
        }
      }
    }
  }
}

extern "C" void kernel_launch(void* const* d_in, const int* in_sizes, int n_in,
                              void* d_out, int out_size, void* d_ws,
                              size_t ws_size, hipStream_t stream) {
  const float* x  = (const float*)d_in[0];
  const int* erow = (const int*)d_in[1];
  const int* ecol = (const int*)d_in[2];
  const float* W1 = (const float*)d_in[4];
  const float* b1 = (const float*)d_in[5];
  const float* W2 = (const float*)d_in[6];
  const float* b2 = (const float*)d_in[7];
  const int E = in_sizes[1];

  char* p = (char*)d_ws;
  auto carve = [&](size_t bytes) {
    char* q = p;
    p += (bytes + 255) & ~(size_t)255;
    return q;
  };
  unsigned* xb = (unsigned*)carve((size_t)N_NODES * 160 * 4);  // 32 MB bf16 x
  unsigned* ax = (unsigned*)carve((size_t)N_NODES * 160 * 4);  // 32 MB
  unsigned* h  = (unsigned*)carve((size_t)N_NODES * 256 * 4);  // 51.2 MB
  unsigned* g2 = (unsigned*)carve((size_t)N_NODES * 256 * 4);  // 51.2 MB
  u16* W1b = (u16*)carve((size_t)HID * KP1 * 2);
  u16* W2b = (u16*)carve((size_t)OUTC * HID * 2);
  int* deg  = (int*)carve((size_t)N_NODES * 4);
  int* rs   = (int*)carve((size_t)(N_NODES + 1) * 4);
  int* cur  = (int*)carve((size_t)N_NODES * 4);
  int* csr_col = (int*)carve((size_t)E * 4);

  (void)hipMemsetAsync(deg, 0, (size_t)N_NODES * 4, stream);
  (void)hipMemsetAsync(cur, 0, (size_t)N_NODES * 4, stream);

  int eb = (E + 255) / 256;
  k_hist<<<eb, 256, 0, stream>>>(erow, E, deg);
  k_scan<<<1, 1024, 0, stream>>>(deg, rs);
  k_scatter<<<eb, 256, 0, stream>>>(erow, ecol, E, rs, cur, csr_col);

  k_convx<<<(N_NODES * 160 + 255) / 256, 256, 0, stream>>>(x, xb);
  k_convw<<<(HID * KP1 + 255) / 256, 256, 0, stream>>>(W1, W1b, INC, KP1, HID * KP1);
  k_convw<<<(OUTC * HID + 255) / 256, 256, 0, stream>>>(W2, W2b, HID, HID, OUTC * HID);

  const int GEMM_GRID = 8 * MCHUNK * 4;   // 1568
  // layer 1: h = relu((A @ x) @ W1^T + b1)
  spmm_x<<<N_NODES / 4, 256, 0, stream>>>((const u32x4*)xb, csr_col, rs, (u32x4*)ax);
  gemm_nt<KP1, true, true><<<GEMM_GRID, 256, 0, stream>>>((const u16*)ax, W1b, b1, (u16*)h, N_NODES);

  // layer 2: out = normalize(A @ (h @ W2^T) + b2)
  gemm_nt<HID, false, false><<<GEMM_GRID, 256, 0, stream>>>((const u16*)h, W2b, nullptr, (u16*)g2, N_NODES);
  spmm_norm<<<N_NODES / 4, 256, 0, stream>>>((const u32x4*)g2, csr_col, rs, b2, (float*)d_out);
}

// Round 6
// 456.797 us; speedup vs baseline: 1.9225x; 1.0245x over previous
//
#include <hip/hip_runtime.h>

#define N_NODES 50000
#define INC 300
#define KP1 320      // padded K for layer-1 GEMM (bf16)
#define HID 512
#define OUTC 512
#define MTILES 391   // ceil(50000/128)
#define MCHUNK 49    // ceil(391/8) m-tiles per XCD

typedef unsigned short u16;
typedef __bf16 bf16;
typedef bf16 bf16x8 __attribute__((ext_vector_type(8)));
typedef float f32x4 __attribute__((ext_vector_type(4)));
typedef float f32x2 __attribute__((ext_vector_type(2)));
typedef unsigned u32x4 __attribute__((ext_vector_type(4)));

__device__ inline u16 f32_to_bf16(float f) {
  unsigned u = __float_as_uint(f);
  u += 0x7FFFu + ((u >> 16) & 1u);   // round-to-nearest-even
  return (u16)(u >> 16);
}

__device__ inline float bf_lo(unsigned u) { return __uint_as_float(u << 16); }
__device__ inline float bf_hi(unsigned u) { return __uint_as_float(u & 0xFFFF0000u); }

__device__ inline void gload_lds16(const void* g, void* l) {
  __builtin_amdgcn_global_load_lds(
      (const __attribute__((address_space(1))) void*)g,
      (__attribute__((address_space(3))) void*)l, 16, 0, 0);
}

// counted wait + hard scheduling fence (rule #18: consumers must not hoist)
#define WAITV(N)                                   \
  do {                                             \
    asm volatile("s_waitcnt vmcnt(" #N ")");       \
    __builtin_amdgcn_sched_barrier(0);             \
  } while (0)

__device__ __forceinline__ void acc8(float a[8], u32x4 q) {
#pragma unroll
  for (int t = 0; t < 4; ++t) {
    a[2 * t]     += bf_lo(q[t]);
    a[2 * t + 1] += bf_hi(q[t]);
  }
}

// ---- latency-pipelined row gather: sum of src[col] over the row's edges ----
// All loads in the hot path are asm global_load_dwordx4 with manual vmcnt so
// the compiler cannot re-serialize them (it did: VGPR_Count=44 in round 5).
// Issue counts are static (padded slots load a duplicate of the last valid
// edge -> same cache line); consume skips padded slots via uniform branch.
template <int RU>
__device__ __forceinline__ void gather_row(
    const u32x4* __restrict__ src, const int* __restrict__ csr_col,
    int s, int cnt, int lane, int lanec, float a[8]) {
  if (cnt <= 0) return;
  const u32x4* base = src + lanec;
  int done = 0;
  while (cnt - done > 32) {              // ultra-rare giant rows
    int c = csr_col[s + done];
    acc8(a, base[(size_t)c * RU]);
    ++done;
  }
  int rem = cnt - done;
  int myc = csr_col[s + done + min(lane, rem - 1)];
  if (rem > 16) {
    u32x4 q[16], p[16];
#pragma unroll
    for (int k = 0; k < 16; ++k) {
      int c = __shfl(myc, k, 64);
      const u32x4* ap = base + (size_t)c * RU;
      asm volatile("global_load_dwordx4 %0, %1, off" : "=v"(q[k]) : "v"(ap));
    }
#pragma unroll
    for (int k = 0; k < 16; ++k) {
      int c = __shfl(myc, min(16 + k, rem - 1), 64);
      const u32x4* ap = base + (size_t)c * RU;
      asm volatile("global_load_dwordx4 %0, %1, off" : "=v"(p[k]) : "v"(ap));
    }
    WAITV(28);
#pragma unroll
    for (int k = 0; k < 4; ++k) acc8(a, q[k]);
    WAITV(24);
#pragma unroll
    for (int k = 4; k < 8; ++k) acc8(a, q[k]);
    WAITV(20);
#pragma unroll
    for (int k = 8; k < 12; ++k) acc8(a, q[k]);
    WAITV(16);
#pragma unroll
    for (int k = 12; k < 16; ++k) acc8(a, q[k]);
    WAITV(12);
#pragma unroll
    for (int k = 0; k < 4; ++k) if (16 + k < rem) acc8(a, p[k]);
    WAITV(8);
#pragma unroll
    for (int k = 4; k < 8; ++k) if (16 + k < rem) acc8(a, p[k]);
    WAITV(4);
#pragma unroll
    for (int k = 8; k < 12; ++k) if (16 + k < rem) acc8(a, p[k]);
    WAITV(0);
#pragma unroll
    for (int k = 12; k < 16; ++k) if (16 + k < rem) acc8(a, p[k]);
  } else {
    u32x4 q[16];
#pragma unroll
    for (int k = 0; k < 16; ++k) {
      int c = __shfl(myc, min(k, rem - 1), 64);
      const u32x4* ap = base + (size_t)c * RU;
      asm volatile("global_load_dwordx4 %0, %1, off" : "=v"(q[k]) : "v"(ap));
    }
    WAITV(12);
#pragma unroll
    for (int k = 0; k < 4; ++k) if (k < rem) acc8(a, q[k]);
    WAITV(8);
#pragma unroll
    for (int k = 4; k < 8; ++k) if (k < rem) acc8(a, q[k]);
    WAITV(4);
#pragma unroll
    for (int k = 8; k < 12; ++k) if (k < rem) acc8(a, q[k]);
    WAITV(0);
#pragma unroll
    for (int k = 12; k < 16; ++k) if (k < rem) acc8(a, q[k]);
  }
}

// ---------------- CSR build ----------------
__global__ void k_hist(const int* __restrict__ erow, int E, int* __restrict__ deg) {
  int i = blockIdx.x * blockDim.x + threadIdx.x;
  if (i < E) atomicAdd(&deg[erow[i]], 1);
}

__global__ __launch_bounds__(1024) void k_scan(const int* __restrict__ deg,
                                               int* __restrict__ rowstart) {
  __shared__ int part[1024];
  int tid = threadIdx.x;
  const int ch = (N_NODES + 1023) / 1024;
  int lo = tid * ch;
  int hi = lo + ch;
  if (lo > N_NODES) lo = N_NODES;
  if (hi > N_NODES) hi = N_NODES;
  int s = 0;
  for (int i = lo; i < hi; ++i) s += deg[i];
  part[tid] = s;
  __syncthreads();
  for (int off = 1; off < 1024; off <<= 1) {
    int v = (tid >= off) ? part[tid - off] : 0;
    __syncthreads();
    part[tid] += v;
    __syncthreads();
  }
  int run = (tid > 0) ? part[tid - 1] : 0;
  for (int i = lo; i < hi; ++i) { rowstart[i] = run; run += deg[i]; }
  if (tid == 1023) rowstart[N_NODES] = part[1023];
}

__global__ void k_scatter(const int* __restrict__ erow, const int* __restrict__ ecol,
                          int E, const int* __restrict__ rowstart,
                          int* __restrict__ cursor, int* __restrict__ csr_col) {
  int i = blockIdx.x * blockDim.x + threadIdx.x;
  if (i < E) {
    int r = erow[i];
    int p = atomicAdd(&cursor[r], 1);
    csr_col[rowstart[r] + p] = ecol[i];
  }
}

// ---------------- weight f32 -> bf16 (zero-padded K) ----------------
__global__ void k_convw(const float* __restrict__ W, u16* __restrict__ Wb,
                        int K, int KPADc, int total) {
  int i = blockIdx.x * blockDim.x + threadIdx.x;
  if (i < total) {
    int r = i / KPADc, k = i - r * KPADc;
    Wb[i] = (k < K) ? f32_to_bf16(W[(size_t)r * K + k]) : (u16)0;
  }
}

// ---------------- x f32[N,300] -> bf16 packed u32 [N,160] (zero-padded) -------
__global__ __launch_bounds__(256) void k_convx(const float* __restrict__ x,
                                               unsigned* __restrict__ xb) {
  int i = blockIdx.x * blockDim.x + threadIdx.x;     // over N*160 u32 slots
  if (i >= N_NODES * 160) return;
  int r = i / 160, j = i - r * 160;
  unsigned out = 0;
  if (2 * j < INC) {
    f32x2 v = __builtin_nontemporal_load((const f32x2*)(x + (size_t)r * INC + 2 * j));
    out = (unsigned)f32_to_bf16(v.x) | ((unsigned)f32_to_bf16(v.y) << 16);
  }
  xb[i] = out;
}

// ---------------- SpMM layer 1: ax = (A @ xb) * 1/deg ------------------------
__global__ __launch_bounds__(256) void spmm_x(
    const u32x4* __restrict__ xb, const int* __restrict__ csr_col,
    const int* __restrict__ rs, u32x4* __restrict__ ax) {
  int r = blockIdx.x * 4 + (threadIdx.x >> 6);
  int lane = threadIdx.x & 63;
  int lanec = min(lane, 39);               // row = 160 u32 = 40 x u32x4
  int s = rs[r], e = rs[r + 1];
  float a[8];
#pragma unroll
  for (int k = 0; k < 8; ++k) a[k] = 0.f;
  gather_row<40>(xb, csr_col, s, e - s, lane, lanec, a);
  float inv = 1.0f / (float)max(e - s, 1);
  u32x4 o;
#pragma unroll
  for (int j = 0; j < 4; ++j) {
    unsigned lo = f32_to_bf16(a[2 * j] * inv);
    unsigned hi = f32_to_bf16(a[2 * j + 1] * inv);
    o[j] = lo | (hi << 16);
  }
  if (lane < 40) ax[(size_t)r * 40 + lane] = o;
}

// ---- SpMM layer 2 fused: out = normalize( (A @ g) * 1/deg + b2 ) -------------
__global__ __launch_bounds__(256) void spmm_norm(
    const u32x4* __restrict__ g, const int* __restrict__ csr_col,
    const int* __restrict__ rs, const float* __restrict__ b2,
    float* __restrict__ out) {
  int r = blockIdx.x * 4 + (threadIdx.x >> 6);
  int lane = threadIdx.x & 63;
  int s = rs[r], e = rs[r + 1];
  float a[8];
#pragma unroll
  for (int k = 0; k < 8; ++k) a[k] = 0.f;
  gather_row<64>(g, csr_col, s, e - s, lane, lane, a);
  float inv = 1.0f / (float)max(e - s, 1);
  f32x4 bv0 = *(const f32x4*)(b2 + lane * 8);
  f32x4 bv1 = *(const f32x4*)(b2 + lane * 8 + 4);
  float v[8];
  v[0] = a[0] * inv + bv0.x; v[1] = a[1] * inv + bv0.y;
  v[2] = a[2] * inv + bv0.z; v[3] = a[3] * inv + bv0.w;
  v[4] = a[4] * inv + bv1.x; v[5] = a[5] * inv + bv1.y;
  v[6] = a[6] * inv + bv1.z; v[7] = a[7] * inv + bv1.w;
  float ss = 0.f;
#pragma unroll
  for (int k = 0; k < 8; ++k) ss += v[k] * v[k];
#pragma unroll
  for (int off = 32; off > 0; off >>= 1) ss += __shfl_xor(ss, off, 64);
  float innrm = 1.0f / fmaxf(sqrtf(ss), 1e-12f);
  f32x4 o0 = {v[0] * innrm, v[1] * innrm, v[2] * innrm, v[3] * innrm};
  f32x4 o1 = {v[4] * innrm, v[5] * innrm, v[6] * innrm, v[7] * innrm};
  float* op = out + (size_t)r * OUTC + lane * 8;
  __builtin_nontemporal_store(o0, (f32x4*)op);
  __builtin_nontemporal_store(o1, (f32x4*)(op + 4));
}

// ---- bf16 MFMA GEMM, XCD-grouped grid, double-buffered LDS prefetch ----------
template <int KPAD, bool RELU, bool HAS_BIAS>
__global__ __launch_bounds__(256) void gemm_nt(
    const u16* __restrict__ A, const u16* __restrict__ B,
    const float* __restrict__ bias, u16* __restrict__ Cout, int M) {
  __shared__ __align__(16) u16 AsB[2][128 * 32];
  __shared__ __align__(16) u16 BsB[2][128 * 32];
  const int bid = blockIdx.x;
  const int xcd = bid & 7;
  const int j = bid >> 3;
  const int mt = xcd * MCHUNK + (j >> 2);
  if (mt >= MTILES) return;
  const int m0 = mt * 128;
  const int n0 = (j & 3) * 128;

  const int tid = threadIdx.x;
  const int wid = tid >> 6;
  const int lane = tid & 63;

  const int srow = lane >> 2;
  const int scol = (lane & 3) * 8;
  const int wm = (wid >> 1) * 64;
  const int wn = (wid & 1) * 64;
  const int fr = lane & 15;
  const int fk = (lane >> 4) * 8;

  auto STAGE = [&](int buf, int k0) {
#pragma unroll
    for (int i = 0; i < 2; ++i) {
      int ar = wid * 32 + i * 16;
      int gm = m0 + ar + srow;
      if (gm >= M) gm = M - 1;
      gload_lds16(A + (size_t)gm * KPAD + k0 + scol, AsB[buf] + ar * 32);
      int gn = n0 + ar + srow;
      gload_lds16(B + (size_t)gn * KPAD + k0 + scol, BsB[buf] + ar * 32);
    }
  };

  f32x4 acc[4][4];
#pragma unroll
  for (int i = 0; i < 4; ++i)
#pragma unroll
    for (int jj = 0; jj < 4; ++jj) acc[i][jj] = (f32x4){0.f, 0.f, 0.f, 0.f};

  constexpr int NT = KPAD / 32;
  STAGE(0, 0);
  __syncthreads();
  int cur = 0;
  for (int t = 0; t < NT; ++t) {
    if (t + 1 < NT) STAGE(cur ^ 1, (t + 1) * 32);   // prefetch next tile
    const u16* As = AsB[cur];
    const u16* Bs = BsB[cur];
    bf16x8 af[4], bfr[4];
#pragma unroll
    for (int r = 0; r < 4; ++r)
      af[r] = *(const bf16x8*)(As + (wm + r * 16 + fr) * 32 + fk);
#pragma unroll
    for (int c = 0; c < 4; ++c)
      bfr[c] = *(const bf16x8*)(Bs + (wn + c * 16 + fr) * 32 + fk);
#pragma unroll
    for (int r = 0; r < 4; ++r)
#pragma unroll
      for (int c = 0; c < 4; ++c)
        acc[r][c] = __builtin_amdgcn_mfma_f32_16x16x32_bf16(af[r], bfr[c],
                                                            acc[r][c], 0, 0, 0);
    __syncthreads();   // drains STAGE vmcnt + this tile's ds_reads
    cur ^= 1;
  }

  const int cr = (lane >> 4) * 4;
#pragma unroll
  for (int c = 0; c < 4; ++c) {
    int gcol = n0 + wn + c * 16 + fr;
    float bv = HAS_BIAS ? bias[gcol] : 0.f;
#pragma unroll
    for (int r = 0; r < 4; ++r) {
#pragma unroll
      for (int jj = 0; jj < 4; ++jj) {
        int gm = m0 + wm + r * 16 + cr + jj;
        if (gm < M) {
          float v = acc[r][c][jj] + bv;
          if (RELU) v = fmaxf(v, 0.f);
          Cout[(size_t)gm * OUTC + gcol] = f32_to_bf16(v);
        }
      }
    }
  }
}

extern "C" void kernel_launch(void* const* d_in, const int* in_sizes, int n_in,
                              void* d_out, int out_size, void* d_ws,
                              size_t ws_size, hipStream_t stream) {
  const float* x  = (const float*)d_in[0];
  const int* erow = (const int*)d_in[1];
  const int* ecol = (const int*)d_in[2];
  const float* W1 = (const float*)d_in[4];
  const float* b1 = (const float*)d_in[5];
  const float* W2 = (const float*)d_in[6];
  const float* b2 = (const float*)d_in[7];
  const int E = in_sizes[1];

  char* p = (char*)d_ws;
  auto carve = [&](size_t bytes) {
    char* q = p;
    p += (bytes + 255) & ~(size_t)255;
    return q;
  };
  unsigned* xb = (unsigned*)carve((size_t)N_NODES * 160 * 4);  // 32 MB bf16 x
  unsigned* ax = (unsigned*)carve((size_t)N_NODES * 160 * 4);  // 32 MB
  unsigned* h  = (unsigned*)carve((size_t)N_NODES * 256 * 4);  // 51.2 MB
  unsigned* g2 = (unsigned*)carve((size_t)N_NODES * 256 * 4);  // 51.2 MB
  u16* W1b = (u16*)carve((size_t)HID * KP1 * 2);
  u16* W2b = (u16*)carve((size_t)OUTC * HID * 2);
  int* deg  = (int*)carve((size_t)N_NODES * 4);
  int* rs   = (int*)carve((size_t)(N_NODES + 1) * 4);
  int* cur  = (int*)carve((size_t)N_NODES * 4);
  int* csr_col = (int*)carve((size_t)E * 4);

  (void)hipMemsetAsync(deg, 0, (size_t)N_NODES * 4, stream);
  (void)hipMemsetAsync(cur, 0, (size_t)N_NODES * 4, stream);

  int eb = (E + 255) / 256;
  k_hist<<<eb, 256, 0, stream>>>(erow, E, deg);
  k_scan<<<1, 1024, 0, stream>>>(deg, rs);
  k_scatter<<<eb, 256, 0, stream>>>(erow, ecol, E, rs, cur, csr_col);

  k_convx<<<(N_NODES * 160 + 255) / 256, 256, 0, stream>>>(x, xb);
  k_convw<<<(HID * KP1 + 255) / 256, 256, 0, stream>>>(W1, W1b, INC, KP1, HID * KP1);
  k_convw<<<(OUTC * HID + 255) / 256, 256, 0, stream>>>(W2, W2b, HID, HID, OUTC * HID);

  const int GEMM_GRID = 8 * MCHUNK * 4;   // 1568
  // layer 1: h = relu((A @ x) @ W1^T + b1)
  spmm_x<<<N_NODES / 4, 256, 0, stream>>>((const u32x4*)xb, csr_col, rs, (u32x4*)ax);
  gemm_nt<KP1, true, true><<<GEMM_GRID, 256, 0, stream>>>((const u16*)ax, W1b, b1, (u16*)h, N_NODES);

  // layer 2: out = normalize(A @ (h @ W2^T) + b2)
  gemm_nt<HID, false, false><<<GEMM_GRID, 256, 0, stream>>>((const u16*)h, W2b, nullptr, (u16*)g2, N_NODES);
  spmm_norm<<<N_NODES / 4, 256, 0, stream>>>((const u32x4*)g2, csr_col, rs, b2, (float*)d_out);
}